// Round 1
// baseline (97.479 us; speedup 1.0000x reference)
//
#include <hip/hip_runtime.h>
#include <stdint.h>

// B=8 S=8192 E=1024 L=64 D=256 H=64; BS=65536; kv cols = 128 (k|v)

typedef __attribute__((__ext_vector_type__(4))) float f32x4;
typedef __attribute__((__ext_vector_type__(8))) short bf16x8;

__device__ __forceinline__ unsigned short f2bf(float f) {
    union { float f; uint32_t u; } v; v.f = f;
    uint32_t u = v.u;
    return (unsigned short)((u + 0x7fffu + ((u >> 16) & 1u)) >> 16);  // RNE
}

// ---------------- prep: Wkv -> bf16 ws, q = (latents @ Wq^T) * 0.125 -> bf16 ws
__global__ __launch_bounds__(256) void prep_kernel(
    const float* __restrict__ latents, const float* __restrict__ Wq,
    const float* __restrict__ Wk, const float* __restrict__ Wv,
    unsigned short* __restrict__ wkv, unsigned short* __restrict__ qbf)
{
    const int blk = blockIdx.x, tid = threadIdx.x;
    if (blk < 128) {
        const float* src = (blk < 64) ? (Wk + (size_t)blk * 1024)
                                      : (Wv + (size_t)(blk - 64) * 1024);
        for (int i = tid; i < 1024; i += 256)
            wkv[(size_t)blk * 1024 + i] = f2bf(src[i]);
    } else {
        const int l = (blk - 128) * 4 + (tid >> 6);
        const int h = tid & 63;
        float a = 0.f;
        for (int d = 0; d < 256; ++d)
            a += latents[l * 256 + d] * Wq[h * 256 + d];
        qbf[l * 64 + h] = f2bf(a * 0.125f);
    }
}

// ---------------- proj: kv[65536][128](bf16) = x(f32->bf16) @ Wkv^T
// 128x128 tile per WG, BK=32, double-buffered LDS, reg-staged (fp32->bf16 cvt).
__global__ __launch_bounds__(256) void proj_kernel(
    const float* __restrict__ x, const unsigned short* __restrict__ wkv,
    unsigned short* __restrict__ kv)
{
    __shared__ unsigned short smem[20480];   // 40 KiB, reused for epilogue
    unsigned short* Ab = smem;               // [2][128][40] bf16 (pad 40 -> 2-way banks)
    unsigned short* Bb = smem + 10240;       // [2][128][40]

    const int tid = threadIdx.x;
    const size_t r0 = (size_t)blockIdx.x * 128;
    const int wave = tid >> 6, lane = tid & 63;
    const int g = lane >> 4, c = lane & 15;
    const int wr = wave >> 1, wc = wave & 1;

    const int rowA = tid >> 3, colA = (tid & 7) * 4;   // 8 lanes x float4 per row
    const int rowB = tid >> 2, colB = (tid & 3) * 8;   // 4 lanes x 16B per row

    f32x4 acc[4][4];
    #pragma unroll
    for (int i = 0; i < 4; ++i)
        #pragma unroll
        for (int j = 0; j < 4; ++j)
            acc[i][j] = f32x4{0.f, 0.f, 0.f, 0.f};

    f32x4 areg[4];
    uint4  breg[2];

    // prologue: stage K-step 0 into buf 0
    #pragma unroll
    for (int i = 0; i < 4; ++i)
        areg[i] = *(const f32x4*)(x + (r0 + rowA + 32 * i) * 1024 + colA);
    #pragma unroll
    for (int j = 0; j < 2; ++j)
        breg[j] = *(const uint4*)(wkv + (size_t)(rowB + 64 * j) * 1024 + colB);
    #pragma unroll
    for (int i = 0; i < 4; ++i) {
        unsigned long long pk =
            (unsigned long long)f2bf(areg[i][0])        |
            ((unsigned long long)f2bf(areg[i][1]) << 16) |
            ((unsigned long long)f2bf(areg[i][2]) << 32) |
            ((unsigned long long)f2bf(areg[i][3]) << 48);
        *(unsigned long long*)&Ab[(rowA + 32 * i) * 40 + colA] = pk;
    }
    #pragma unroll
    for (int j = 0; j < 2; ++j)
        *(uint4*)&Bb[(rowB + 64 * j) * 40 + colB] = breg[j];
    __syncthreads();

    for (int t = 0; t < 32; ++t) {
        const int buf = t & 1;
        if (t < 31) {   // issue next-tile global loads before compute
            const int e0 = (t + 1) * 32;
            #pragma unroll
            for (int i = 0; i < 4; ++i)
                areg[i] = *(const f32x4*)(x + (r0 + rowA + 32 * i) * 1024 + e0 + colA);
            #pragma unroll
            for (int j = 0; j < 2; ++j)
                breg[j] = *(const uint4*)(wkv + (size_t)(rowB + 64 * j) * 1024 + e0 + colB);
        }
        // compute on buf: 8 ds_read_b128 + 16 mfma per wave
        bf16x8 af[4], bfr[4];
        #pragma unroll
        for (int ml = 0; ml < 4; ++ml)
            af[ml] = *(const bf16x8*)&Ab[(buf * 128 + 64 * wr + 16 * ml + c) * 40 + 8 * g];
        #pragma unroll
        for (int nc = 0; nc < 4; ++nc)
            bfr[nc] = *(const bf16x8*)&Bb[(buf * 128 + 64 * wc + 16 * nc + c) * 40 + 8 * g];
        #pragma unroll
        for (int ml = 0; ml < 4; ++ml)
            #pragma unroll
            for (int nc = 0; nc < 4; ++nc)
                acc[ml][nc] = __builtin_amdgcn_mfma_f32_16x16x32_bf16(
                    af[ml], bfr[nc], acc[ml][nc], 0, 0, 0);
        if (t < 31) {   // cvt + write into other buffer
            const int nb = buf ^ 1;
            #pragma unroll
            for (int i = 0; i < 4; ++i) {
                unsigned long long pk =
                    (unsigned long long)f2bf(areg[i][0])        |
                    ((unsigned long long)f2bf(areg[i][1]) << 16) |
                    ((unsigned long long)f2bf(areg[i][2]) << 32) |
                    ((unsigned long long)f2bf(areg[i][3]) << 48);
                *(unsigned long long*)&Ab[(nb * 128 + rowA + 32 * i) * 40 + colA] = pk;
            }
            #pragma unroll
            for (int j = 0; j < 2; ++j)
                *(uint4*)&Bb[(nb * 128 + rowB + 64 * j) * 40 + colB] = breg[j];
        }
        __syncthreads();
    }

    // epilogue: acc -> LDS (bf16) -> coalesced 16B global stores
    unsigned short* Cs = smem;   // [128][136]
    #pragma unroll
    for (int ml = 0; ml < 4; ++ml)
        #pragma unroll
        for (int nc = 0; nc < 4; ++nc)
            #pragma unroll
            for (int r = 0; r < 4; ++r)
                Cs[(64 * wr + 16 * ml + 4 * g + r) * 136 + 64 * wc + 16 * nc + c] =
                    f2bf(acc[ml][nc][r]);
    __syncthreads();
    const int rowO = tid >> 4, colO = (tid & 15) * 8;
    #pragma unroll
    for (int i = 0; i < 8; ++i) {
        const int row = rowO + 16 * i;
        uint4 vv = *(const uint4*)&Cs[row * 136 + colO];
        *(uint4*)(kv + (r0 + row) * 128 + colO) = vv;
    }
}

// ---------------- attn: per (b, 128-key chunk): scores=q@k^T, chunk softmax, O=P@v
__global__ __launch_bounds__(256) void attn_kernel(
    const unsigned short* __restrict__ kv, const unsigned short* __restrict__ qbf,
    float* __restrict__ Opart, float* __restrict__ mpart, float* __restrict__ spart)
{
    __shared__ unsigned short kvs[128][136];
    __shared__ unsigned short qs[64][72];
    __shared__ unsigned short Ps[64][136];
    __shared__ float red[4][64];
    __shared__ float Mrow[64];

    const int tid = threadIdx.x, wave = tid >> 6, lane = tid & 63;
    const int g = lane >> 4, c = lane & 15;
    const int b = blockIdx.x >> 6, ch = blockIdx.x & 63;
    const size_t base = (size_t)b * 8192 + (size_t)ch * 128;

    {   // stage kv chunk + q
        const int rowK = tid >> 4, colK = (tid & 15) * 8;
        #pragma unroll
        for (int i = 0; i < 8; ++i) {
            const int row = rowK + 16 * i;
            *(uint4*)&kvs[row][colK] = *(const uint4*)(kv + (base + row) * 128 + colK);
        }
        const int rowQ = tid >> 3, colQ = (tid & 7) * 8;
        #pragma unroll
        for (int i = 0; i < 2; ++i) {
            const int row = rowQ + 32 * i;
            *(uint4*)&qs[row][colQ] = *(const uint4*)(qbf + row * 64 + colQ);
        }
    }
    __syncthreads();

    // scores: wave w covers s in [32w, 32w+32); D[row=l, col=s]
    f32x4 sc[4][2];
    #pragma unroll
    for (int ml = 0; ml < 4; ++ml)
        #pragma unroll
        for (int ns = 0; ns < 2; ++ns)
            sc[ml][ns] = f32x4{0.f, 0.f, 0.f, 0.f};
    #pragma unroll
    for (int k0 = 0; k0 < 2; ++k0) {
        bf16x8 aq[4];
        #pragma unroll
        for (int ml = 0; ml < 4; ++ml)
            aq[ml] = *(const bf16x8*)&qs[16 * ml + c][32 * k0 + 8 * g];
        #pragma unroll
        for (int ns = 0; ns < 2; ++ns) {
            bf16x8 bk = *(const bf16x8*)&kvs[32 * wave + 16 * ns + c][32 * k0 + 8 * g];
            #pragma unroll
            for (int ml = 0; ml < 4; ++ml)
                sc[ml][ns] = __builtin_amdgcn_mfma_f32_16x16x32_bf16(
                    aq[ml], bk, sc[ml][ns], 0, 0, 0);
        }
    }

    // row max: lane-local over ns, shuffle over the 16 s-lanes, combine 4 waves
    float mloc[4][4];
    #pragma unroll
    for (int ml = 0; ml < 4; ++ml)
        #pragma unroll
        for (int r = 0; r < 4; ++r)
            mloc[ml][r] = fmaxf(sc[ml][0][r], sc[ml][1][r]);
    #pragma unroll
    for (int off = 1; off <= 8; off <<= 1)
        #pragma unroll
        for (int ml = 0; ml < 4; ++ml)
            #pragma unroll
            for (int r = 0; r < 4; ++r)
                mloc[ml][r] = fmaxf(mloc[ml][r], __shfl_xor(mloc[ml][r], off));
    if (c == 0)
        #pragma unroll
        for (int ml = 0; ml < 4; ++ml)
            #pragma unroll
            for (int r = 0; r < 4; ++r)
                red[wave][16 * ml + 4 * g + r] = mloc[ml][r];
    __syncthreads();
    if (tid < 64) {
        float m = red[0][tid];
        m = fmaxf(m, red[1][tid]); m = fmaxf(m, red[2][tid]); m = fmaxf(m, red[3][tid]);
        Mrow[tid] = m;
    }
    __syncthreads();

    // P = exp(sc - M) (bf16 into LDS), row sums
    float ssum[4][4];
    #pragma unroll
    for (int ml = 0; ml < 4; ++ml)
        #pragma unroll
        for (int r = 0; r < 4; ++r)
            ssum[ml][r] = 0.f;
    #pragma unroll
    for (int ml = 0; ml < 4; ++ml)
        #pragma unroll
        for (int r = 0; r < 4; ++r) {
            const int l = 16 * ml + 4 * g + r;
            const float mr = Mrow[l];
            #pragma unroll
            for (int ns = 0; ns < 2; ++ns) {
                float p = __expf(sc[ml][ns][r] - mr);
                unsigned short pb = f2bf(p);
                Ps[l][32 * wave + 16 * ns + c] = pb;
                union { uint32_t u; float f; } pv; pv.u = (uint32_t)pb << 16;
                ssum[ml][r] += pv.f;   // sum the rounded value for consistency
            }
        }
    #pragma unroll
    for (int off = 1; off <= 8; off <<= 1)
        #pragma unroll
        for (int ml = 0; ml < 4; ++ml)
            #pragma unroll
            for (int r = 0; r < 4; ++r)
                ssum[ml][r] += __shfl_xor(ssum[ml][r], off);
    if (c == 0)
        #pragma unroll
        for (int ml = 0; ml < 4; ++ml)
            #pragma unroll
            for (int r = 0; r < 4; ++r)
                red[wave][16 * ml + 4 * g + r] = ssum[ml][r];
    __syncthreads();
    if (tid < 64) {
        const float s = red[0][tid] + red[1][tid] + red[2][tid] + red[3][tid];
        mpart[(size_t)blockIdx.x * 64 + tid] = Mrow[tid];
        spart[(size_t)blockIdx.x * 64 + tid] = s;
    }

    // PV: wave w owns l in [16w,16w+16); D[row=l, col=h]
    f32x4 o[4];
    #pragma unroll
    for (int nh = 0; nh < 4; ++nh) o[nh] = f32x4{0.f, 0.f, 0.f, 0.f};
    #pragma unroll
    for (int ks = 0; ks < 4; ++ks) {
        bf16x8 ap = *(const bf16x8*)&Ps[16 * wave + c][32 * ks + 8 * g];
        #pragma unroll
        for (int nh = 0; nh < 4; ++nh) {
            bf16x8 bv;
            #pragma unroll
            for (int j = 0; j < 8; ++j)
                bv[j] = (short)kvs[32 * ks + 8 * g + j][64 + 16 * nh + c];
            o[nh] = __builtin_amdgcn_mfma_f32_16x16x32_bf16(ap, bv, o[nh], 0, 0, 0);
        }
    }
    const size_t pb = (size_t)blockIdx.x * 64;
    #pragma unroll
    for (int nh = 0; nh < 4; ++nh)
        #pragma unroll
        for (int r = 0; r < 4; ++r) {
            const int l = 16 * wave + 4 * g + r;
            const int h = 16 * nh + c;
            Opart[(pb + l) * 64 + h] = o[nh][r];
        }
}

// ---------------- combine: flash merge of 64 chunk partials per (b,l)
__global__ __launch_bounds__(64) void combine_kernel(
    const float* __restrict__ Opart, const float* __restrict__ mpart,
    const float* __restrict__ spart, float* __restrict__ out)
{
    const int b = blockIdx.x >> 6, l = blockIdx.x & 63, h = threadIdx.x;
    float M = -3.0e38f;
    for (int ch = 0; ch < 64; ++ch)
        M = fmaxf(M, mpart[((size_t)(b * 64 + ch)) * 64 + l]);
    float den = 0.f, acc = 0.f;
    for (int ch = 0; ch < 64; ++ch) {
        const size_t idx = ((size_t)(b * 64 + ch)) * 64 + l;
        const float w = __expf(mpart[idx] - M);
        den += w * spart[idx];
        acc += w * Opart[idx * 64 + h];
    }
    out[((size_t)blockIdx.x) * 64 + h] = acc / den;
}

extern "C" void kernel_launch(void* const* d_in, const int* in_sizes, int n_in,
                              void* d_out, int out_size, void* d_ws, size_t ws_size,
                              hipStream_t stream)
{
    const float* x       = (const float*)d_in[0];  // [8,8192,1024]
    const float* latents = (const float*)d_in[1];  // [64,256]
    const float* Wq      = (const float*)d_in[2];  // [64,256]
    const float* Wk      = (const float*)d_in[3];  // [64,1024]
    const float* Wv      = (const float*)d_in[4];  // [64,1024]
    float* out = (float*)d_out;                    // [8,64,64] f32
    char* ws = (char*)d_ws;

    unsigned short* wkv = (unsigned short*)(ws);                      // 262144 B
    unsigned short* qbf = (unsigned short*)(ws + 262144);             // 8192 B
    unsigned short* kvb = (unsigned short*)(ws + 270336);             // 16777216 B
    float* Opart = (float*)(ws + 270336 + 16777216);                  // 8388608 B
    float* mpart = (float*)(ws + 270336 + 16777216 + 8388608);        // 131072 B
    float* spart = (float*)(ws + 270336 + 16777216 + 8388608 + 131072);

    hipLaunchKernelGGL(prep_kernel, dim3(144), dim3(256), 0, stream,
                       latents, Wq, Wk, Wv, wkv, qbf);
    hipLaunchKernelGGL(proj_kernel, dim3(512), dim3(256), 0, stream, x, wkv, kvb);
    hipLaunchKernelGGL(attn_kernel, dim3(512), dim3(256), 0, stream,
                       kvb, qbf, Opart, mpart, spart);
    hipLaunchKernelGGL(combine_kernel, dim3(512), dim3(64), 0, stream,
                       Opart, mpart, spart, out);
}

// Round 2
// 81.750 us; speedup vs baseline: 1.1924x; 1.1924x over previous
//
#include <hip/hip_runtime.h>
#include <stdint.h>

// B=8 S=8192 E=1024 L=64 D=256 H=64; BS=65536; kv cols = 128 (k|v)

typedef __attribute__((__ext_vector_type__(4))) float f32x4;
typedef __attribute__((__ext_vector_type__(8))) short bf16x8;

__device__ __forceinline__ unsigned short f2bf(float f) {
    union { float f; uint32_t u; } v; v.f = f;
    uint32_t u = v.u;
    return (unsigned short)((u + 0x7fffu + ((u >> 16) & 1u)) >> 16);  // RNE
}

// ---------------- prep: Wkv -> bf16 ws, q = (latents @ Wq^T) * 0.125 -> bf16 ws
__global__ __launch_bounds__(256) void prep_kernel(
    const float* __restrict__ latents, const float* __restrict__ Wq,
    const float* __restrict__ Wk, const float* __restrict__ Wv,
    unsigned short* __restrict__ wkv, unsigned short* __restrict__ qbf)
{
    const int blk = blockIdx.x, tid = threadIdx.x;
    if (blk < 128) {
        const float* src = (blk < 64) ? (Wk + (size_t)blk * 1024)
                                      : (Wv + (size_t)(blk - 64) * 1024);
        for (int i = tid; i < 1024; i += 256)
            wkv[(size_t)blk * 1024 + i] = f2bf(src[i]);
    } else {
        const int l = (blk - 128) * 4 + (tid >> 6);
        const int h = tid & 63;
        float a = 0.f;
        for (int d = 0; d < 256; ++d)
            a += latents[l * 256 + d] * Wq[h * 256 + d];
        qbf[l * 64 + h] = f2bf(a * 0.125f);
    }
}

// ---------------- fused: per (b, 128-key chunk):
//   kv tile (128 tokens x 128 cols) = x(f32->bf16) @ Wkv^T  (into LDS, bf16)
//   then scores=q@k^T, chunk softmax, O=P@v -> partials
__global__ __launch_bounds__(256) void fused_kernel(
    const float* __restrict__ x, const unsigned short* __restrict__ wkv,
    const unsigned short* __restrict__ qbf,
    float* __restrict__ Opart, float* __restrict__ mpart, float* __restrict__ spart)
{
    __shared__ unsigned short smem[33792];   // 67.5 KiB
    unsigned short* Ab = smem;               // [2][128][40] bf16 (main loop)
    unsigned short* Bb = smem + 10240;       // [2][128][40]
    unsigned short* Cs = smem;               // [128][136]  (aliases Ab/Bb after loop)
    unsigned short* qs = smem + 20480;       // [64][72]
    unsigned short* Ps = smem + 25088;       // [64][136]
    __shared__ float red[4][64];
    __shared__ float Mrow[64];

    const int tid = threadIdx.x;
    const int wave = tid >> 6, lane = tid & 63;
    const int g = lane >> 4, c = lane & 15;
    const int wr = wave >> 1, wc = wave & 1;
    const size_t r0 = (size_t)blockIdx.x * 128;   // token row base (b*8192 + ch*128)

    // stage q (read after the main loop; barriers in between cover visibility)
    {
        const int rowQ = tid >> 3, colQ = (tid & 7) * 8;
        #pragma unroll
        for (int i = 0; i < 2; ++i) {
            const int row = rowQ + 32 * i;
            *(uint4*)&qs[row * 72 + colQ] = *(const uint4*)(qbf + row * 64 + colQ);
        }
    }

    const int rowA = tid >> 3, colA = (tid & 7) * 4;   // 8 lanes x float4 per row
    const int rowB = tid >> 2, colB = (tid & 3) * 8;   // 4 lanes x 16B per row

    f32x4 acc[4][4];
    #pragma unroll
    for (int i = 0; i < 4; ++i)
        #pragma unroll
        for (int j = 0; j < 4; ++j)
            acc[i][j] = f32x4{0.f, 0.f, 0.f, 0.f};

    f32x4 areg[4];
    uint4  breg[2];

    // prologue: stage K-step 0 into buf 0
    #pragma unroll
    for (int i = 0; i < 4; ++i)
        areg[i] = *(const f32x4*)(x + (r0 + rowA + 32 * i) * 1024 + colA);
    #pragma unroll
    for (int j = 0; j < 2; ++j)
        breg[j] = *(const uint4*)(wkv + (size_t)(rowB + 64 * j) * 1024 + colB);
    #pragma unroll
    for (int i = 0; i < 4; ++i) {
        unsigned long long pk =
            (unsigned long long)f2bf(areg[i][0])        |
            ((unsigned long long)f2bf(areg[i][1]) << 16) |
            ((unsigned long long)f2bf(areg[i][2]) << 32) |
            ((unsigned long long)f2bf(areg[i][3]) << 48);
        *(unsigned long long*)&Ab[(rowA + 32 * i) * 40 + colA] = pk;
    }
    #pragma unroll
    for (int j = 0; j < 2; ++j)
        *(uint4*)&Bb[(rowB + 64 * j) * 40 + colB] = breg[j];
    __syncthreads();

    for (int t = 0; t < 32; ++t) {
        const int buf = t & 1;
        if (t < 31) {   // issue next-tile global loads before compute
            const int e0 = (t + 1) * 32;
            #pragma unroll
            for (int i = 0; i < 4; ++i)
                areg[i] = *(const f32x4*)(x + (r0 + rowA + 32 * i) * 1024 + e0 + colA);
            #pragma unroll
            for (int j = 0; j < 2; ++j)
                breg[j] = *(const uint4*)(wkv + (size_t)(rowB + 64 * j) * 1024 + e0 + colB);
        }
        // compute on buf: 8 ds_read_b128 + 16 mfma per wave
        bf16x8 af[4], bfr[4];
        #pragma unroll
        for (int ml = 0; ml < 4; ++ml)
            af[ml] = *(const bf16x8*)&Ab[(buf * 128 + 64 * wr + 16 * ml + c) * 40 + 8 * g];
        #pragma unroll
        for (int nc = 0; nc < 4; ++nc)
            bfr[nc] = *(const bf16x8*)&Bb[(buf * 128 + 64 * wc + 16 * nc + c) * 40 + 8 * g];
        #pragma unroll
        for (int ml = 0; ml < 4; ++ml)
            #pragma unroll
            for (int nc = 0; nc < 4; ++nc)
                acc[ml][nc] = __builtin_amdgcn_mfma_f32_16x16x32_bf16(
                    af[ml], bfr[nc], acc[ml][nc], 0, 0, 0);
        if (t < 31) {   // cvt + write into other buffer
            const int nb = buf ^ 1;
            #pragma unroll
            for (int i = 0; i < 4; ++i) {
                unsigned long long pk =
                    (unsigned long long)f2bf(areg[i][0])        |
                    ((unsigned long long)f2bf(areg[i][1]) << 16) |
                    ((unsigned long long)f2bf(areg[i][2]) << 32) |
                    ((unsigned long long)f2bf(areg[i][3]) << 48);
                *(unsigned long long*)&Ab[(nb * 128 + rowA + 32 * i) * 40 + colA] = pk;
            }
            #pragma unroll
            for (int j = 0; j < 2; ++j)
                *(uint4*)&Bb[(nb * 128 + rowB + 64 * j) * 40 + colB] = breg[j];
        }
        __syncthreads();
    }

    // kv tile -> LDS (bf16), aliasing the staging buffers (all reads drained)
    #pragma unroll
    for (int ml = 0; ml < 4; ++ml)
        #pragma unroll
        for (int nc = 0; nc < 4; ++nc)
            #pragma unroll
            for (int r = 0; r < 4; ++r)
                Cs[(64 * wr + 16 * ml + 4 * g + r) * 136 + 64 * wc + 16 * nc + c] =
                    f2bf(acc[ml][nc][r]);
    __syncthreads();

    // ---- attention on the LDS tile: cols 0..63 = k, 64..127 = v ----
    // scores: wave w covers s in [32w, 32w+32); D[row=l, col=s]
    f32x4 sc[4][2];
    #pragma unroll
    for (int ml = 0; ml < 4; ++ml)
        #pragma unroll
        for (int ns = 0; ns < 2; ++ns)
            sc[ml][ns] = f32x4{0.f, 0.f, 0.f, 0.f};
    #pragma unroll
    for (int k0 = 0; k0 < 2; ++k0) {
        bf16x8 aq[4];
        #pragma unroll
        for (int ml = 0; ml < 4; ++ml)
            aq[ml] = *(const bf16x8*)&qs[(16 * ml + c) * 72 + 32 * k0 + 8 * g];
        #pragma unroll
        for (int ns = 0; ns < 2; ++ns) {
            bf16x8 bk = *(const bf16x8*)&Cs[(32 * wave + 16 * ns + c) * 136 + 32 * k0 + 8 * g];
            #pragma unroll
            for (int ml = 0; ml < 4; ++ml)
                sc[ml][ns] = __builtin_amdgcn_mfma_f32_16x16x32_bf16(
                    aq[ml], bk, sc[ml][ns], 0, 0, 0);
        }
    }

    // row max: lane-local over ns, shuffle over the 16 s-lanes, combine 4 waves
    float mloc[4][4];
    #pragma unroll
    for (int ml = 0; ml < 4; ++ml)
        #pragma unroll
        for (int r = 0; r < 4; ++r)
            mloc[ml][r] = fmaxf(sc[ml][0][r], sc[ml][1][r]);
    #pragma unroll
    for (int off = 1; off <= 8; off <<= 1)
        #pragma unroll
        for (int ml = 0; ml < 4; ++ml)
            #pragma unroll
            for (int r = 0; r < 4; ++r)
                mloc[ml][r] = fmaxf(mloc[ml][r], __shfl_xor(mloc[ml][r], off));
    if (c == 0)
        #pragma unroll
        for (int ml = 0; ml < 4; ++ml)
            #pragma unroll
            for (int r = 0; r < 4; ++r)
                red[wave][16 * ml + 4 * g + r] = mloc[ml][r];
    __syncthreads();
    if (tid < 64) {
        float m = red[0][tid];
        m = fmaxf(m, red[1][tid]); m = fmaxf(m, red[2][tid]); m = fmaxf(m, red[3][tid]);
        Mrow[tid] = m;
    }
    __syncthreads();

    // P = exp(sc - M) (bf16 into LDS), row sums
    float ssum[4][4];
    #pragma unroll
    for (int ml = 0; ml < 4; ++ml)
        #pragma unroll
        for (int r = 0; r < 4; ++r)
            ssum[ml][r] = 0.f;
    #pragma unroll
    for (int ml = 0; ml < 4; ++ml)
        #pragma unroll
        for (int r = 0; r < 4; ++r) {
            const int l = 16 * ml + 4 * g + r;
            const float mr = Mrow[l];
            #pragma unroll
            for (int ns = 0; ns < 2; ++ns) {
                float p = __expf(sc[ml][ns][r] - mr);
                unsigned short pb = f2bf(p);
                Ps[l * 136 + 32 * wave + 16 * ns + c] = pb;
                union { uint32_t u; float f; } pv; pv.u = (uint32_t)pb << 16;
                ssum[ml][r] += pv.f;   // sum the rounded value for consistency
            }
        }
    #pragma unroll
    for (int off = 1; off <= 8; off <<= 1)
        #pragma unroll
        for (int ml = 0; ml < 4; ++ml)
            #pragma unroll
            for (int r = 0; r < 4; ++r)
                ssum[ml][r] += __shfl_xor(ssum[ml][r], off);
    if (c == 0)
        #pragma unroll
        for (int ml = 0; ml < 4; ++ml)
            #pragma unroll
            for (int r = 0; r < 4; ++r)
                red[wave][16 * ml + 4 * g + r] = ssum[ml][r];
    __syncthreads();
    if (tid < 64) {
        const float s = red[0][tid] + red[1][tid] + red[2][tid] + red[3][tid];
        mpart[(size_t)blockIdx.x * 64 + tid] = Mrow[tid];
        spart[(size_t)blockIdx.x * 64 + tid] = s;
    }

    // PV: wave w owns l in [16w,16w+16); D[row=l, col=h]
    f32x4 o[4];
    #pragma unroll
    for (int nh = 0; nh < 4; ++nh) o[nh] = f32x4{0.f, 0.f, 0.f, 0.f};
    #pragma unroll
    for (int ks = 0; ks < 4; ++ks) {
        bf16x8 ap = *(const bf16x8*)&Ps[(16 * wave + c) * 136 + 32 * ks + 8 * g];
        #pragma unroll
        for (int nh = 0; nh < 4; ++nh) {
            bf16x8 bv;
            #pragma unroll
            for (int j = 0; j < 8; ++j)
                bv[j] = (short)Cs[(32 * ks + 8 * g + j) * 136 + 64 + 16 * nh + c];
            o[nh] = __builtin_amdgcn_mfma_f32_16x16x32_bf16(ap, bv, o[nh], 0, 0, 0);
        }
    }
    const size_t pb = (size_t)blockIdx.x * 64;
    #pragma unroll
    for (int nh = 0; nh < 4; ++nh)
        #pragma unroll
        for (int r = 0; r < 4; ++r) {
            const int l = 16 * wave + 4 * g + r;
            const int h = 16 * nh + c;
            Opart[(pb + l) * 64 + h] = o[nh][r];
        }
}

// ---------------- combine: flash merge of 64 chunk partials per (b,l)
__global__ __launch_bounds__(64) void combine_kernel(
    const float* __restrict__ Opart, const float* __restrict__ mpart,
    const float* __restrict__ spart, float* __restrict__ out)
{
    const int b = blockIdx.x >> 6, l = blockIdx.x & 63, h = threadIdx.x;
    float M = -3.0e38f;
    #pragma unroll 8
    for (int ch = 0; ch < 64; ++ch)
        M = fmaxf(M, mpart[((size_t)(b * 64 + ch)) * 64 + l]);
    float den = 0.f, acc = 0.f;
    #pragma unroll 8
    for (int ch = 0; ch < 64; ++ch) {
        const size_t idx = ((size_t)(b * 64 + ch)) * 64 + l;
        const float w = __expf(mpart[idx] - M);
        den += w * spart[idx];
        acc += w * Opart[idx * 64 + h];
    }
    out[((size_t)blockIdx.x) * 64 + h] = acc / den;
}

extern "C" void kernel_launch(void* const* d_in, const int* in_sizes, int n_in,
                              void* d_out, int out_size, void* d_ws, size_t ws_size,
                              hipStream_t stream)
{
    const float* x       = (const float*)d_in[0];  // [8,8192,1024]
    const float* latents = (const float*)d_in[1];  // [64,256]
    const float* Wq      = (const float*)d_in[2];  // [64,256]
    const float* Wk      = (const float*)d_in[3];  // [64,1024]
    const float* Wv      = (const float*)d_in[4];  // [64,1024]
    float* out = (float*)d_out;                    // [8,64,64] f32
    char* ws = (char*)d_ws;

    unsigned short* wkv = (unsigned short*)(ws);                 // 262144 B
    unsigned short* qbf = (unsigned short*)(ws + 262144);        // 8192 B
    float* Opart = (float*)(ws + 270336);                        // 8388608 B
    float* mpart = (float*)(ws + 270336 + 8388608);              // 131072 B
    float* spart = (float*)(ws + 270336 + 8388608 + 131072);     // 131072 B

    hipLaunchKernelGGL(prep_kernel, dim3(144), dim3(256), 0, stream,
                       latents, Wq, Wk, Wv, wkv, qbf);
    hipLaunchKernelGGL(fused_kernel, dim3(512), dim3(256), 0, stream,
                       x, wkv, qbf, Opart, mpart, spart);
    hipLaunchKernelGGL(combine_kernel, dim3(512), dim3(64), 0, stream,
                       Opart, mpart, spart, out);
}